// Round 4
// baseline (337.068 us; speedup 1.0000x reference)
//
#include <hip/hip_runtime.h>
#include <hip/hip_bf16.h>

typedef __bf16 bf16x8 __attribute__((ext_vector_type(8)));
typedef __bf16 bf16x4 __attribute__((ext_vector_type(4)));
typedef float  f32x4  __attribute__((ext_vector_type(4)));

#define GRID 256
// d_out offsets (floats)
#define O_FINAL 0
#define O_H     512
#define O_C     1049088      // 512 + 4*256*1024
#define O_NORM  2097664      // O_C + 4*256*1024

// ---------------- grid barrier (slots zeroed by hipMemsetAsync each call) ----------------
__device__ __forceinline__ void gridbar(int* slot) {
  __syncthreads();
  if (threadIdx.x == 0) {
    __threadfence();   // release: prior stores visible device-wide
    __hip_atomic_fetch_add(slot, 1, __ATOMIC_RELEASE, __HIP_MEMORY_SCOPE_AGENT);
    while (__hip_atomic_load(slot, __ATOMIC_ACQUIRE, __HIP_MEMORY_SCOPE_AGENT) < GRID)
      __builtin_amdgcn_s_sleep(8);
    __threadfence();   // acquire
  }
  __syncthreads();
}

// ---------------- pipelined LDS-staged GEMM sub-loop ----------------
// Block tile: 64 rows (r0..) x [16 cols x 4 gates] of A[256xK]@W[4096xK]^T.
// 16 waves: wave = rf(0..3) x gg(0..3); each wave one 16x16 frag (gate gg).
// Double-buffered LDS (2 x 16 KB), 2-deep global prefetch, 1 sync/step.
// W fp32 converted to bf16 during staging. XOR-swizzled LDS rows (128 B).
template<int NK, int SA, int SW>
__device__ __forceinline__ void gemm_pipe(const __bf16* __restrict__ A,
                                          const float* __restrict__ W,
                                          int r0, int j0, char* lds,
                                          f32x4& acc) {
  const int t = threadIdx.x, lane = t & 63, wave = t >> 6;
  const int rf = wave & 3, gg = wave >> 2;
  // staging: W 64 rows x 64 k fp32 (all 1024 thr, float4 each)
  const int wtr = t >> 4, wch = t & 15;
  const float* wsrc = W + (size_t)((wtr >> 4) * 1024 + j0 + (wtr & 15)) * SW + wch * 4;
  const int woff = wtr * 128 + ((((wch >> 1) ^ (wtr & 7)) << 4) | ((wch & 1) << 3));
  // staging: A 64 rows x 64 k bf16 (threads < 512, bf16x8 each)
  const int atr = t >> 3, ach = t & 7;
  const __bf16* asrc = A + (size_t)(r0 + atr) * SA + ach * 8;
  const int aoff = 8192 + atr * 128 + (((ach ^ (atr & 7)) << 4));
  const bool do_a = (t < 512);
  // fragment read addresses
  const int arow = rf * 16 + (lane & 15);
  const int wrow = gg * 16 + (lane & 15);
  const int ksel = lane >> 4;

  float4 wreg[2]; bf16x8 areg[2];
  wreg[0] = *(const float4*)wsrc;
  if (do_a) areg[0] = *(const bf16x8*)asrc;
  wreg[1] = *(const float4*)(wsrc + 64);
  if (do_a) areg[1] = *(const bf16x8*)(asrc + 64);

#pragma unroll 2
  for (int s = 0; s < NK; ++s) {
    const int p = s & 1;
    char* buf = lds + p * 16384;
    bf16x4 wv;
    wv[0] = (__bf16)wreg[p].x; wv[1] = (__bf16)wreg[p].y;
    wv[2] = (__bf16)wreg[p].z; wv[3] = (__bf16)wreg[p].w;
    *(bf16x4*)(buf + woff) = wv;
    if (do_a) *(bf16x8*)(buf + aoff) = areg[p];
    if (s + 2 < NK) {
      wreg[p] = *(const float4*)(wsrc + (size_t)(s + 2) * 64);
      if (do_a) areg[p] = *(const bf16x8*)(asrc + (size_t)(s + 2) * 64);
    }
    __syncthreads();
#pragma unroll
    for (int s2 = 0; s2 < 2; ++s2) {
      const int chk = s2 * 4 + ksel;
      bf16x8 af = *(const bf16x8*)(buf + 8192 + arow * 128 + ((chk ^ (arow & 7)) << 4));
      bf16x8 wf = *(const bf16x8*)(buf +        wrow * 128 + ((chk ^ (wrow & 7)) << 4));
      acc = __builtin_amdgcn_mfma_f32_16x16x32_bf16(af, wf, acc, 0, 0, 0);
    }
  }
}

// ---------------- one LSTM layer phase (GEMM x2 + gates) ----------------
template<int KA>
__device__ __forceinline__ void layer_phase(const __bf16* __restrict__ A1,
                                            const float* __restrict__ W1,
                                            const __bf16* __restrict__ A2,
                                            const float* __restrict__ W2,
                                            const float* __restrict__ bi,
                                            const float* __restrict__ bh,
                                            const float* __restrict__ c0l,
                                            float* __restrict__ h_out,
                                            float* __restrict__ c_out,
                                            __bf16* __restrict__ hb_out,
                                            char* lds) {
  const int t = threadIdx.x, lane = t & 63, wave = t >> 6;
  const int rf = wave & 3, gg = wave >> 2;
  const int cb = blockIdx.x & 63, rb = blockIdx.x >> 6;
  const int j0 = cb * 16, r0 = rb * 64;
  f32x4 acc = {0.f, 0.f, 0.f, 0.f};
  gemm_pipe<KA / 64, KA, KA>(A1, W1, r0, j0, lds, acc);
  gemm_pipe<16, 1024, 1024>(A2, W2, r0, j0, lds, acc);

  const int col = j0 + (lane & 15);
  const int rbase = r0 + rf * 16 + ((lane >> 4) << 2);
  const int cg = gg * 1024 + col;
  const float bsum = bi[cg] + bh[cg];
  const int eidx = ((lane >> 4) << 2) * 16 + (lane & 15);
  float* exch = (float*)(lds + 32768);
  if (gg) {
#pragma unroll
    for (int q = 0; q < 4; ++q)
      exch[((gg - 1) * 4 + rf) * 256 + eidx + q * 16] = acc[q] + bsum;
  }
  __syncthreads();
  if (gg == 0) {
#pragma unroll
    for (int q = 0; q < 4; ++q) {
      const int row = rbase + q;
      float gi = acc[q] + bsum;
      float gf = exch[(0 * 4 + rf) * 256 + eidx + q * 16];
      float gv = exch[(1 * 4 + rf) * 256 + eidx + q * 16];
      float go = exch[(2 * 4 + rf) * 256 + eidx + q * 16];
      float si = 1.f / (1.f + __expf(-gi));
      float sf = 1.f / (1.f + __expf(-gf));
      float so = 1.f / (1.f + __expf(-go));
      float c2 = sf * c0l[(size_t)row * 1024 + col] + si * tanhf(gv);
      float h2 = so * tanhf(c2);
      h_out[(size_t)row * 1024 + col] = h2;
      c_out[(size_t)row * 1024 + col] = c2;
      hb_out[(size_t)row * 1024 + col] = (__bf16)h2;
    }
  }
}

// ---------------- mega kernel ----------------
__global__ __launch_bounds__(1024, 4) void k_mega(
    const float* __restrict__ inp,  const float* __restrict__ h0,
    const float* __restrict__ c0,   const float* __restrict__ AO,
    const float* __restrict__ Wemb, const float* __restrict__ bemb,
    const float* __restrict__ Wattn,
    const float* __restrict__ Wih0, const float* __restrict__ Whh0,
    const float* __restrict__ bih0, const float* __restrict__ bhh0,
    const float* __restrict__ Wih_r,const float* __restrict__ Whh_r,
    const float* __restrict__ bih_r,const float* __restrict__ bhh_r,
    const float* __restrict__ Wout, const float* __restrict__ bout,
    float* __restrict__ out, int* __restrict__ bar,
    __bf16* __restrict__ xb, __bf16* __restrict__ h0b, __bf16* __restrict__ hb) {
  __shared__ char smem[45056];
  const int t = threadIdx.x, lane = t & 63, wave = t >> 6;
  const int b = blockIdx.x;

  // ======== P0: per-batch-row scores + softmax + applied_last + emb + h0 cvt ========
  {
    float* sc_l = (float*)smem;             // 256 f
    float* red  = (float*)(smem + 1024);    // 4 f
    float* nv_l = (float*)(smem + 1088);    // 256 f
    const float* wy = Wattn + 1024;
    float4 wv[4];
#pragma unroll
    for (int q = 0; q < 4; ++q) wv[q] = *(const float4*)(wy + lane * 4 + 256 * q);
#pragma unroll 2
    for (int pp = 0; pp < 16; ++pp) {
      const int pos = pp * 16 + wave;
      const float4* rp = (const float4*)(AO + ((size_t)pos * 256 + b) * 1024);
      float a = 0.f;
#pragma unroll
      for (int q = 0; q < 4; ++q) {
        float4 v = rp[lane + 64 * q];
        a += v.x * wv[q].x + v.y * wv[q].y + v.z * wv[q].z + v.w * wv[q].w;
      }
#pragma unroll
      for (int off = 32; off; off >>= 1) a += __shfl_xor(a, off, 64);
      if (lane == 0) sc_l[pos] = a;
    }
    __syncthreads();
    if (t < 256) {
      float s = sc_l[t];
      float m = s;
#pragma unroll
      for (int off = 32; off; off >>= 1) m = fmaxf(m, __shfl_xor(m, off, 64));
      if (lane == 0) red[wave] = m;
      __syncthreads();
      m = fmaxf(fmaxf(red[0], red[1]), fmaxf(red[2], red[3]));
      float e = __expf(s - m);
      float sum = e;
#pragma unroll
      for (int off = 32; off; off >>= 1) sum += __shfl_xor(sum, off, 64);
      __syncthreads();
      if (lane == 0) red[wave] = sum;
      __syncthreads();
      sum = red[0] + red[1] + red[2] + red[3];
      float nv = e / sum;
      nv_l[t] = nv;
      out[O_NORM + b * 256 + t] = nv;
    } else {
      __syncthreads(); __syncthreads(); __syncthreads();
    }
    __syncthreads();
    // applied_last: col t over last 32 positions (L2-hot re-read)
    float accA = 0.f;
#pragma unroll 4
    for (int i = 0; i < 32; ++i)
      accA += nv_l[224 + i] * AO[((size_t)(224 + i) * 256 + b) * 1024 + t];
    xb[(size_t)b * 1536 + t] = (__bf16)(8.0f * accA);
    // embedding
    if (t < 512) {
      float e2 = inp[b * 2] * Wemb[t * 2] + inp[b * 2 + 1] * Wemb[t * 2 + 1] + bemb[t];
      xb[(size_t)b * 1536 + 1024 + t] = (__bf16)fmaxf(e2, 0.f);
    }
    // h0 -> bf16
#pragma unroll
    for (int l = 0; l < 4; ++l)
      h0b[(size_t)l * 262144 + b * 1024 + t] = (__bf16)h0[((size_t)l * 256 + b) * 1024 + t];
  }
  gridbar(bar + 0 * 32);

  // ======== layers ========
  layer_phase<1536>(xb, Wih0, h0b, Whh0, bih0, bhh0, c0,
                    out + O_H, out + O_C, hb, smem);
  gridbar(bar + 1 * 32);
  for (int l = 1; l < 4; ++l) {
    layer_phase<1024>(hb + (size_t)(l - 1) * 262144,
                      Wih_r + (size_t)(l - 1) * 4194304,
                      h0b + (size_t)l * 262144,
                      Whh_r + (size_t)(l - 1) * 4194304,
                      bih_r + (size_t)(l - 1) * 4096,
                      bhh_r + (size_t)(l - 1) * 4096,
                      c0 + (size_t)l * 262144,
                      out + O_H + (size_t)l * 262144,
                      out + O_C + (size_t)l * 262144,
                      hb + (size_t)l * 262144, smem);
    gridbar(bar + (l + 1) * 32);
  }

  // ======== final ========
  if (blockIdx.x < 64 && wave < 4) {
    const float* h3 = out + O_H + 3 * 262144;
    const int bb = blockIdx.x * 4 + wave;
    const float4* hp = (const float4*)(h3 + (size_t)bb * 1024);
    const float4* w0 = (const float4*)Wout;
    const float4* w1 = (const float4*)(Wout + 1024);
    float a0 = 0.f, a1 = 0.f;
#pragma unroll
    for (int q = 0; q < 4; ++q) {
      float4 hv = hp[lane + 64 * q];
      float4 v0 = w0[lane + 64 * q];
      float4 v1 = w1[lane + 64 * q];
      a0 += hv.x * v0.x + hv.y * v0.y + hv.z * v0.z + hv.w * v0.w;
      a1 += hv.x * v1.x + hv.y * v1.y + hv.z * v1.z + hv.w * v1.w;
    }
#pragma unroll
    for (int off = 32; off; off >>= 1) {
      a0 += __shfl_xor(a0, off, 64);
      a1 += __shfl_xor(a1, off, 64);
    }
    if (lane == 0) {
      out[bb * 2]     = a0 + bout[0];
      out[bb * 2 + 1] = a1 + bout[1];
    }
  }
}

extern "C" void kernel_launch(void* const* d_in, const int* in_sizes, int n_in,
                              void* d_out, int out_size, void* d_ws, size_t ws_size,
                              hipStream_t stream) {
  const float* inp    = (const float*)d_in[0];
  const float* h0     = (const float*)d_in[1];
  const float* c0     = (const float*)d_in[2];
  const float* AO     = (const float*)d_in[3];
  const float* Wemb   = (const float*)d_in[4];
  const float* bemb   = (const float*)d_in[5];
  const float* Wattn  = (const float*)d_in[6];
  // d_in[7] = b_attn (cancels in softmax)
  const float* Wih0   = (const float*)d_in[8];
  const float* Whh0   = (const float*)d_in[9];
  const float* bih0   = (const float*)d_in[10];
  const float* bhh0   = (const float*)d_in[11];
  const float* Wih_r  = (const float*)d_in[12];
  const float* Whh_r  = (const float*)d_in[13];
  const float* bih_r  = (const float*)d_in[14];
  const float* bhh_r  = (const float*)d_in[15];
  const float* Wout   = (const float*)d_in[16];
  const float* bout   = (const float*)d_in[17];

  float* out = (float*)d_out;
  char* ws = (char*)d_ws;

  int*    bar = (int*)ws;                                   // 4 KB barrier slots
  __bf16* xb  = (__bf16*)(ws + 4096);                       // 768 KB [256,1536]
  __bf16* h0b = (__bf16*)(ws + 4096 + 786432);              // 2 MB [4,256,1024]
  __bf16* hb  = (__bf16*)(ws + 4096 + 786432 + 2097152);    // 2 MB [4,256,1024]

  hipMemsetAsync(bar, 0, 4096, stream);
  k_mega<<<GRID, 1024, 0, stream>>>(inp, h0, c0, AO, Wemb, bemb, Wattn,
                                    Wih0, Whh0, bih0, bhh0,
                                    Wih_r, Whh_r, bih_r, bhh_r,
                                    Wout, bout, out, bar, xb, h0b, hb);
}

// Round 5
// 289.365 us; speedup vs baseline: 1.1649x; 1.1649x over previous
//
#include <hip/hip_runtime.h>
#include <hip/hip_bf16.h>

typedef __bf16 bf16x8 __attribute__((ext_vector_type(8)));
typedef __bf16 bf16x4 __attribute__((ext_vector_type(4)));
typedef float  f32x4  __attribute__((ext_vector_type(4)));

#define GRID 256
// d_out offsets (floats)
#define O_FINAL 0
#define O_H     512
#define O_C     1049088      // 512 + 4*256*1024
#define O_NORM  2097664      // O_C + 4*256*1024

// ---- grid barrier: relaxed sc1 polling (NO per-poll cache invalidate),
// ---- one release RMW on entry, one acquire load on exit. Slots zeroed by
// ---- hipMemsetAsync before each launch.
__device__ __forceinline__ void gridbar(int* slot) {
  __syncthreads();
  if (threadIdx.x == 0) {
    __hip_atomic_fetch_add(slot, 1, __ATOMIC_ACQ_REL, __HIP_MEMORY_SCOPE_AGENT);
    while (__hip_atomic_load(slot, __ATOMIC_RELAXED, __HIP_MEMORY_SCOPE_AGENT) < GRID)
      __builtin_amdgcn_s_sleep(4);
    (void)__hip_atomic_load(slot, __ATOMIC_ACQUIRE, __HIP_MEMORY_SCOPE_AGENT);
  }
  __syncthreads();
}

// ---- R3-proven staged tile GEMM: 512 thr, 64 rows x (16 cols x 4 gates),
// ---- XOR-swizzled LDS, 1-deep reg prefetch, 2 syncs/step.
template<int K>
__device__ __forceinline__ void tile_gemm(const __bf16* __restrict__ A,
                                          const float* __restrict__ W,
                                          int r0, int j0,
                                          __bf16* __restrict__ At,
                                          __bf16* __restrict__ Wt,
                                          f32x4 acc[2]) {
  const int t = threadIdx.x;
  const int lane = t & 63, wave = t >> 6;
  const int rf = wave & 3, gg = wave >> 2;
  const int tr = t >> 3, chunk = t & 7;          // staging: row 0..63, 8-elem chunk
  const int wrow = (tr >> 4) * 1024 + j0 + (tr & 15);
  const float*  wsrc = W + (size_t)wrow * K + chunk * 8;
  const __bf16* asrc = A + (size_t)(r0 + tr) * K + chunk * 8;
  const int sw_off = (chunk ^ (tr & 7)) << 4;    // swizzled byte offset in 128B row
  char* wdst = (char*)Wt + tr * 128 + sw_off;
  char* adst = (char*)At + tr * 128 + sw_off;
  const int a_tr  = rf * 16 + (lane & 15);
  const int w_tr0 = gg * 32 + (lane & 15);
  const int w_tr1 = w_tr0 + 16;
  const int ksel  = lane >> 4;                   // 0..3

  float4 wreg0 = *(const float4*)wsrc;
  float4 wreg1 = *(const float4*)(wsrc + 4);
  bf16x8 areg  = *(const bf16x8*)asrc;

  constexpr int NK = K / 64;
#pragma unroll 2
  for (int step = 0; step < NK; ++step) {
    __syncthreads();                             // prior tile fully consumed
    bf16x8 wv;
    wv[0] = (__bf16)wreg0.x; wv[1] = (__bf16)wreg0.y;
    wv[2] = (__bf16)wreg0.z; wv[3] = (__bf16)wreg0.w;
    wv[4] = (__bf16)wreg1.x; wv[5] = (__bf16)wreg1.y;
    wv[6] = (__bf16)wreg1.z; wv[7] = (__bf16)wreg1.w;
    *(bf16x8*)wdst = wv;
    *(bf16x8*)adst = areg;
    __syncthreads();
    if (step + 1 < NK) {
      wreg0 = *(const float4*)(wsrc + (step + 1) * 64);
      wreg1 = *(const float4*)(wsrc + (step + 1) * 64 + 4);
      areg  = *(const bf16x8*)(asrc + (step + 1) * 64);
    }
#pragma unroll
    for (int s = 0; s < 2; ++s) {
      const int chk = s * 4 + ksel;
      bf16x8 af  = *(const bf16x8*)((char*)At + a_tr  * 128 + ((chk ^ (a_tr  & 7)) << 4));
      bf16x8 wf0 = *(const bf16x8*)((char*)Wt + w_tr0 * 128 + ((chk ^ (w_tr0 & 7)) << 4));
      bf16x8 wf1 = *(const bf16x8*)((char*)Wt + w_tr1 * 128 + ((chk ^ (w_tr1 & 7)) << 4));
      acc[0] = __builtin_amdgcn_mfma_f32_16x16x32_bf16(af, wf0, acc[0], 0, 0, 0);
      acc[1] = __builtin_amdgcn_mfma_f32_16x16x32_bf16(af, wf1, acc[1], 0, 0, 0);
    }
  }
}

// ---- one LSTM layer: acc = A1@W1^T + h0@W2^T; gates epilogue ----
template<int KA>
__device__ __forceinline__ void layer_phase(const __bf16* __restrict__ A1,
                                            const float* __restrict__ W1,
                                            const __bf16* __restrict__ A2,
                                            const float* __restrict__ W2,
                                            const float* __restrict__ bi,
                                            const float* __restrict__ bh,
                                            const float* __restrict__ c0l,
                                            float* __restrict__ h_out,
                                            float* __restrict__ c_out,
                                            __bf16* __restrict__ hb_out,
                                            char* smem) {
  __bf16* At  = (__bf16*)smem;
  __bf16* Wt  = (__bf16*)(smem + 8192);
  float*  exch = (float*)(smem + 16384);
  const int t = threadIdx.x, lane = t & 63, wave = t >> 6;
  const int rf = wave & 3, gg = wave >> 2;            // gg in {0,1}: gates {i,f} / {g,o}
  const int cb = blockIdx.x & 63, rb = blockIdx.x >> 6;
  const int j0 = cb * 16, r0 = rb * 64;
  f32x4 acc[2] = {};
  tile_gemm<KA>(A1, W1, r0, j0, At, Wt, acc);
  tile_gemm<1024>(A2, W2, r0, j0, At, Wt, acc);
  const int col = j0 + (lane & 15);
  const int rbase = r0 + rf * 16 + ((lane >> 4) << 2);
  const int eidx = ((lane >> 4) << 2) * 16 + (lane & 15);
  const float b0 = bi[(gg * 2) * 1024 + col]     + bh[(gg * 2) * 1024 + col];
  const float b1 = bi[(gg * 2 + 1) * 1024 + col] + bh[(gg * 2 + 1) * 1024 + col];
  if (gg == 1) {
#pragma unroll
    for (int gi = 0; gi < 2; ++gi)
#pragma unroll
      for (int q = 0; q < 4; ++q)
        exch[(rf * 2 + gi) * 256 + eidx + q * 16] = acc[gi][q] + (gi ? b1 : b0);
  }
  __syncthreads();
  if (gg == 0) {
#pragma unroll
    for (int q = 0; q < 4; ++q) {
      const int row = rbase + q;
      float giv = acc[0][q] + b0;
      float gfv = acc[1][q] + b1;
      float gvv = exch[(rf * 2 + 0) * 256 + eidx + q * 16];
      float gov = exch[(rf * 2 + 1) * 256 + eidx + q * 16];
      float si = 1.f / (1.f + __expf(-giv));
      float sf = 1.f / (1.f + __expf(-gfv));
      float so = 1.f / (1.f + __expf(-gov));
      float c2 = sf * c0l[(size_t)row * 1024 + col] + si * tanhf(gvv);
      float h2 = so * tanhf(c2);
      h_out[(size_t)row * 1024 + col] = h2;
      c_out[(size_t)row * 1024 + col] = c2;
      hb_out[(size_t)row * 1024 + col] = (__bf16)h2;
    }
  }
}

// ---- persistent kernel: P0 (scores+softmax+applied+emb+cvt) -> 4 layers -> final
__global__ __launch_bounds__(512, 2) void k_chain(
    const float* __restrict__ inp,  const float* __restrict__ h0,
    const float* __restrict__ c0,   const float* __restrict__ AO,
    const float* __restrict__ Wemb, const float* __restrict__ bemb,
    const float* __restrict__ Wattn,
    const float* __restrict__ Wih0, const float* __restrict__ Whh0,
    const float* __restrict__ bih0, const float* __restrict__ bhh0,
    const float* __restrict__ Wih_r,const float* __restrict__ Whh_r,
    const float* __restrict__ bih_r,const float* __restrict__ bhh_r,
    const float* __restrict__ Wout, const float* __restrict__ bout,
    float* __restrict__ out, int* __restrict__ bar,
    __bf16* __restrict__ xb, __bf16* __restrict__ h0b, __bf16* __restrict__ hb) {
  __shared__ char smem[24576];
  const int t = threadIdx.x, lane = t & 63, wave = t >> 6;
  const int b = blockIdx.x;

  // ======== P0: per-b scores + softmax + applied_last + emb + h0 cvt ========
  {
    float* sc_l = (float*)smem;             // 256 f
    float* red  = (float*)(smem + 1024);    // 4 f
    float* nv_l = (float*)(smem + 1088);    // 256 f
    const float* wy = Wattn + 1024;
    float4 wv[4];
#pragma unroll
    for (int q = 0; q < 4; ++q) wv[q] = *(const float4*)(wy + lane * 4 + 256 * q);
#pragma unroll 2
    for (int s = 0; s < 8; ++s) {
      const int p0 = s * 32 + wave * 4;
      float a4[4];
#pragma unroll
      for (int rr = 0; rr < 4; ++rr) {
        const float4* rp = (const float4*)(AO + ((size_t)(p0 + rr) * 256 + b) * 1024);
        float a = 0.f;
#pragma unroll
        for (int q = 0; q < 4; ++q) {
          float4 v = rp[lane + 64 * q];
          a += v.x * wv[q].x + v.y * wv[q].y + v.z * wv[q].z + v.w * wv[q].w;
        }
        a4[rr] = a;
      }
#pragma unroll
      for (int rr = 0; rr < 4; ++rr) {
        float a = a4[rr];
#pragma unroll
        for (int off = 32; off; off >>= 1) a += __shfl_xor(a, off, 64);
        if (lane == 0) sc_l[p0 + rr] = a;
      }
    }
    __syncthreads();
    if (t < 256) {
      float s = sc_l[t];
      float m = s;
#pragma unroll
      for (int off = 32; off; off >>= 1) m = fmaxf(m, __shfl_xor(m, off, 64));
      if (lane == 0) red[wave] = m;
      __syncthreads();
      m = fmaxf(fmaxf(red[0], red[1]), fmaxf(red[2], red[3]));
      float e = __expf(s - m);
      float sum = e;
#pragma unroll
      for (int off = 32; off; off >>= 1) sum += __shfl_xor(sum, off, 64);
      __syncthreads();
      if (lane == 0) red[wave] = sum;
      __syncthreads();
      sum = red[0] + red[1] + red[2] + red[3];
      float nv = e / sum;
      nv_l[t] = nv;
      out[O_NORM + b * 256 + t] = nv;
    } else {
      __syncthreads(); __syncthreads(); __syncthreads();
    }
    __syncthreads();
    // applied_last: 1024 cols over 512 thr (AO tail rows are L2/L3-hot)
    float a0 = 0.f, a1 = 0.f;
    const float* base = AO + ((size_t)224 * 256 + b) * 1024;
#pragma unroll 4
    for (int i = 0; i < 32; ++i) {
      float w = nv_l[224 + i];
      const float* rp = base + (size_t)i * 262144;
      a0 += w * rp[t];
      a1 += w * rp[t + 512];
    }
    xb[(size_t)b * 1536 + t]       = (__bf16)(8.0f * a0);
    xb[(size_t)b * 1536 + t + 512] = (__bf16)(8.0f * a1);
    // embedding (512 cols, 1 per thread)
    {
      float e2 = inp[b * 2] * Wemb[t * 2] + inp[b * 2 + 1] * Wemb[t * 2 + 1] + bemb[t];
      xb[(size_t)b * 1536 + 1024 + t] = (__bf16)fmaxf(e2, 0.f);
    }
    // h0 -> bf16 (this block's b, all 4 layers)
#pragma unroll
    for (int l = 0; l < 4; ++l)
#pragma unroll
      for (int r = 0; r < 2; ++r) {
        int idx = t + r * 512;
        h0b[(size_t)l * 262144 + b * 1024 + idx] =
            (__bf16)h0[((size_t)l * 256 + b) * 1024 + idx];
      }
  }
  gridbar(bar + 0 * 32);

  // ======== layers ========
  layer_phase<1536>(xb, Wih0, h0b, Whh0, bih0, bhh0, c0,
                    out + O_H, out + O_C, hb, smem);
  gridbar(bar + 1 * 32);
  for (int l = 1; l < 4; ++l) {
    layer_phase<1024>(hb + (size_t)(l - 1) * 262144,
                      Wih_r + (size_t)(l - 1) * 4194304,
                      h0b + (size_t)l * 262144,
                      Whh_r + (size_t)(l - 1) * 4194304,
                      bih_r + (size_t)(l - 1) * 4096,
                      bhh_r + (size_t)(l - 1) * 4096,
                      c0 + (size_t)l * 262144,
                      out + O_H + (size_t)l * 262144,
                      out + O_C + (size_t)l * 262144,
                      hb + (size_t)l * 262144, smem);
    gridbar(bar + (l + 1) * 32);
  }

  // ======== final: out[b,:2] = h3[b,:] @ Wout^T + bout ========
  if (blockIdx.x < 32) {
    const float* h3 = out + O_H + 3 * 262144;
    const int bb = blockIdx.x * 8 + wave;
    const float4* hp = (const float4*)(h3 + (size_t)bb * 1024);
    const float4* w0 = (const float4*)Wout;
    const float4* w1 = (const float4*)(Wout + 1024);
    float a0 = 0.f, a1 = 0.f;
#pragma unroll
    for (int q = 0; q < 4; ++q) {
      float4 hv = hp[lane + 64 * q];
      float4 v0 = w0[lane + 64 * q];
      float4 v1 = w1[lane + 64 * q];
      a0 += hv.x * v0.x + hv.y * v0.y + hv.z * v0.z + hv.w * v0.w;
      a1 += hv.x * v1.x + hv.y * v1.y + hv.z * v1.z + hv.w * v1.w;
    }
#pragma unroll
    for (int off = 32; off; off >>= 1) {
      a0 += __shfl_xor(a0, off, 64);
      a1 += __shfl_xor(a1, off, 64);
    }
    if (lane == 0) {
      out[bb * 2]     = a0 + bout[0];
      out[bb * 2 + 1] = a1 + bout[1];
    }
  }
}

extern "C" void kernel_launch(void* const* d_in, const int* in_sizes, int n_in,
                              void* d_out, int out_size, void* d_ws, size_t ws_size,
                              hipStream_t stream) {
  const float* inp    = (const float*)d_in[0];
  const float* h0     = (const float*)d_in[1];
  const float* c0     = (const float*)d_in[2];
  const float* AO     = (const float*)d_in[3];
  const float* Wemb   = (const float*)d_in[4];
  const float* bemb   = (const float*)d_in[5];
  const float* Wattn  = (const float*)d_in[6];
  // d_in[7] = b_attn (cancels in softmax)
  const float* Wih0   = (const float*)d_in[8];
  const float* Whh0   = (const float*)d_in[9];
  const float* bih0   = (const float*)d_in[10];
  const float* bhh0   = (const float*)d_in[11];
  const float* Wih_r  = (const float*)d_in[12];
  const float* Whh_r  = (const float*)d_in[13];
  const float* bih_r  = (const float*)d_in[14];
  const float* bhh_r  = (const float*)d_in[15];
  const float* Wout   = (const float*)d_in[16];
  const float* bout   = (const float*)d_in[17];

  float* out = (float*)d_out;
  char* ws = (char*)d_ws;

  int*    bar = (int*)ws;                                   // 4 KB barrier slots
  __bf16* xb  = (__bf16*)(ws + 4096);                       // 768 KB [256,1536]
  __bf16* h0b = (__bf16*)(ws + 4096 + 786432);              // 2 MB [4,256,1024]
  __bf16* hb  = (__bf16*)(ws + 4096 + 786432 + 2097152);    // 2 MB [4,256,1024]

  hipMemsetAsync(bar, 0, 4096, stream);
  k_chain<<<GRID, 512, 0, stream>>>(inp, h0, c0, AO, Wemb, bemb, Wattn,
                                    Wih0, Whh0, bih0, bhh0,
                                    Wih_r, Whh_r, bih_r, bhh_r,
                                    Wout, bout, out, bar, xb, h0b, hb);
}